// Round 1
// baseline (199.703 us; speedup 1.0000x reference)
//
#include <hip/hip_runtime.h>

#define NCH    40
#define MORD   16
#define NR     17
#define NBINS  257
#define FPB    128               // frames per block = threads per block (2 waves)
#define NCHUNK 8                 // 8 chunks x 32 bins = bins 0..255
#define PAIRW  65                // LDS words per frame-pair row (64 data + 1 pad)
#define OSTR   21                // out-staging row stride in floats (conflict-free)

// ---------------- compile-time table generation (double precision) ----------------
namespace cfg {

constexpr double PI  = 3.14159265358979323846264338327950288;
constexpr double LN2 = 0.693147180559945309417232121458176568;

constexpr double cexp(double x) {
    double t = 1.0, s = 1.0;
    for (int i = 1; i < 40; ++i) { t *= x / i; s += t; }
    return s;
}

constexpr double clog(double z) {
    double lg = 0.0;
    while (z > 1.4142135623730951) { z *= 0.5; lg += LN2; }
    while (z < 0.7071067811865476) { z *= 2.0; lg -= LN2; }
    double u = (z - 1.0) / (z + 1.0), u2 = u * u, t = u, s = u;
    for (int k = 1; k < 24; ++k) { t *= u2; s += t / (2.0 * k + 1.0); }
    return lg + 2.0 * s;
}

constexpr double ccos(double x) {
    double tp = 2.0 * PI;
    double q = x / tp;
    long long k = (long long)(q + (q >= 0.0 ? 0.5 : -0.5));
    double r = x - (double)k * tp;
    double r2 = r * r, t = 1.0, s = 1.0;
    for (int i = 1; i < 20; ++i) { t *= -r2 / ((2.0 * i - 1.0) * (2.0 * i)); s += t; }
    return s;
}

constexpr double csin(double x) { return ccos(x - PI / 2.0); }

struct Tab {
    int   start[43];     // start[c] = first bin with t_b > c
    int   chan[257];     // segment id c(b), 0..40
    float w[257];        // t_b - c(b), in [0,1)
    float eql[NCH];
    float lift[NR];
    float ctf[NR][21];   // folded cosine: r[l] = sum_j ctf[l][j]*(ys[j] +- ys[41-j])
    constexpr Tab() : start(), chan(), w(), eql(), lift(), ctf() {
        const double lmax  = clog(87.0 / 7.0);
        const double U1127 = lmax / 41.0;
        for (int c = 0; c <= 41; ++c) {
            double thr = 22.4 * (cexp((double)c * U1127) - 1.0);
            int s = (int)thr + 1;
            if (s < 1) s = 1;
            if (s > 256) s = 256;
            start[c] = s;
        }
        start[42] = start[41];
        for (int c = 0; c <= 40; ++c) {
            for (int b = start[c]; b < start[c + 1]; ++b) {
                double mel = 1127.0 * clog(1.0 + (double)b * 31.25 / 700.0);
                double t   = mel / (1127.0 * U1127);
                w[b] = (float)(t - (double)c);
                chan[b] = c;
            }
        }
        for (int c = 0; c < NCH; ++c) {
            double cf = 700.0 * (cexp((double)(c + 1) * U1127) - 1.0);
            double f2 = cf * cf;
            double e  = f2 / (f2 + 160000.0);
            e = e * e * (f2 + 1440000.0) / (f2 + 9610000.0);
            eql[c] = (float)e;
        }
        for (int m = 0; m < NR; ++m)
            lift[m] = (float)(1.0 + 11.0 * csin(PI * (double)m / 22.0));
        lift[0] = 2.0f;
        for (int l = 0; l < NR; ++l)
            for (int j = 0; j <= 20; ++j) {
                double s = (j == 0) ? 1.0 : 2.0;
                ctf[l][j] = (float)(s * ccos(PI * (double)(j * l) / 41.0) / 82.0);
            }
    }
};

constexpr Tab T{};

} // namespace cfg

// async global->LDS DMA, 4 bytes/lane, linear LDS dest (wave-uniform base + lane*4)
__device__ __forceinline__ void gload_lds4(const float* g, float* l) {
    __builtin_amdgcn_global_load_lds(
        (const __attribute__((address_space(1))) unsigned int*)g,
        (__attribute__((address_space(3))) unsigned int*)l, 4, 0, 0);
}

// Layout: frame pair g occupies LDS words [g*65, g*65+64): frame 2g at +0..31,
// frame 2g+1 at +32..63 for the current 32-bin chunk. Reader thread t (frame t)
// reads word (t>>1)*65 + (t&1)*32 + p  -> bank (u+p)&31, 2-way only => free.
__global__ __launch_bounds__(FPB, 2) void plp_kernel(const float* __restrict__ x,
                                                     float* __restrict__ out,
                                                     int nframes)
{
    using cfg::T;
    __shared__ float slab[2][64][PAIRW];         // 33280 B -> 4 blocks/CU, 8 waves/CU

    const int tid = threadIdx.x;
    const long long F0 = (long long)blockIdx.x * FPB;

    const int w = tid >> 6;                      // wave 0/1
    const int l = tid & 63;
    const int s = l >> 5;                        // half-wave: frame parity within pair
    const int j = l & 31;                        // bin-in-chunk lane

    // stage chunk c (bins 32c..32c+31) of this wave's 64 frames into buffer b
    auto stage = [&](int c, int b) {
        const float* gp0 = x + (c << 5) + j;
        #pragma unroll
        for (int r = 0; r < 32; ++r) {
            const int g = (w << 5) + r;          // pair row 0..63
            long long fg = F0 + 2 * g + s;
            if (fg > (long long)nframes - 1) fg = (long long)nframes - 1;
            gload_lds4(gp0 + fg * NBINS, &slab[b][g][0]);
        }
    };

    stage(0, 0);

    const int u   = tid >> 1;
    const int v32 = (tid & 1) << 5;

    float fb[NCH];
    #pragma unroll
    for (int c = 0; c < NCH; ++c) fb[c] = 0.f;

    __syncthreads();                             // chunk 0 landed (vmcnt drained)

    // ---- chunked, double-buffered sparse mel filterbank (fp32, literal weights) ----
    #pragma unroll
    for (int c8 = 0; c8 < NCHUNK; ++c8) {
        if (c8 + 1 < NCHUNK) stage(c8 + 1, (c8 + 1) & 1);   // prefetch under compute
        const float* fr = &slab[c8 & 1][u][v32];
        #pragma unroll
        for (int p = 0; p < 32; ++p) {
            const int bb = (c8 << 5) + p;        // bin index 0..255 (bin 0: weight 0)
            if (bb == 0) continue;
            const float xv = fr[p];
            const int   ch = T.chan[bb];
            const float wa = T.w[bb];
            if (ch < NCH) fb[ch]     = fmaf(wa, xv, fb[ch]);
            if (ch >= 1)  fb[ch - 1] = fmaf(1.0f - wa, xv, fb[ch - 1]);
        }
        if (c8 + 1 < NCHUNK) __syncthreads();    // next buffer ready / this one free
    }

    // ---- equal-loudness + cube-root compression (fast log/exp), ys in regs ----
    float yv[NCH];
    #pragma unroll
    for (int c = 0; c < NCH; ++c) {
        float v = fmaxf(fb[c], 1e-5f) * T.eql[c];
        yv[c] = __expf(0.33f * __logf(v));
    }

    // ---- even/odd fold of y (42 taps incl. duplicated edges) ----
    float ye[21], yo[21];
    ye[0] = yv[0] + yv[39];  yo[0] = yv[0] - yv[39];       // ys[0], ys[41]
    #pragma unroll
    for (int jj = 1; jj <= 20; ++jj) {
        float aa = yv[jj - 1], bb = yv[40 - jj];           // ys[j], ys[41-j]
        ye[jj] = aa + bb;  yo[jj] = aa - bb;
    }

    // ---- folded cosine transform: 17 lags x 21 taps, literal coefficients ----
    float r[NR];
    #pragma unroll
    for (int lg = 0; lg < NR; ++lg) {
        const float* yy = (lg & 1) ? yo : ye;
        float acc = 0.f;
        #pragma unroll
        for (int jj = 0; jj <= 20; ++jj) acc = fmaf(T.ctf[lg][jj], yy[jj], acc);
        r[lg] = acc;
    }

    // ---- Levinson-Durbin (unrolled, v_rcp) ----
    float a[MORD];
    #pragma unroll
    for (int i = 0; i < MORD; ++i) a[i] = 0.f;
    float E = r[0];
    #pragma unroll
    for (int i = 1; i <= MORD; ++i) {
        float acc = r[i];
        #pragma unroll
        for (int jj = 0; jj < i - 1; ++jj) acc = fmaf(a[jj], r[i - 1 - jj], acc);
        float k = -acc * __builtin_amdgcn_rcpf(E);
        const int half = (i - 1) / 2;
        #pragma unroll
        for (int jj = 0; jj < half; ++jj) {
            float t1 = a[jj], t2 = a[i - 2 - jj];
            a[jj]         = fmaf(k, t2, t1);
            a[i - 2 - jj] = fmaf(k, t1, t2);
        }
        if ((i - 1) & 1) a[half] = fmaf(k, a[half], a[half]);
        a[i - 1] = k;
        E = E * (1.f - k * k);
    }

    // ---- cepstrum (c[0] unused; ccs[k]=k*cc[k] keeps inner fma literal-free) ----
    float cc[NR], ccs[NR];
    #pragma unroll
    for (int m = 1; m <= MORD; ++m) {
        float acc = 0.f;
        #pragma unroll
        for (int k2 = 1; k2 < m; ++k2)
            acc = fmaf(ccs[k2], a[m - k2 - 1], acc);
        float cm = -(a[m - 1] + acc * (1.0f / (float)m));
        cc[m]  = cm;
        ccs[m] = (float)m * cm;
    }

    // ---- out-staging through the (now idle) slab for coalesced dwordx4 stores ----
    // writes hit the buf0 region (words 0..2687 < 4160) - disjoint from any lagging
    // wave still reading buf1 in the last chunk, so no barrier needed before them.
    float* ob = &slab[0][0][0];
    #pragma unroll
    for (int m = 1; m <= MORD; ++m)
        ob[tid * OSTR + (m - 1)] = cc[m] * T.lift[m];     // 2-way banks only (21 odd)
    __syncthreads();

    float4* out4 = (float4*)out;
    const long long gbase4 = F0 << 2;                      // float4 index of block base
    const long long lim4   = ((long long)nframes) << 2;
    #pragma unroll
    for (int q = 0; q < 4; ++q) {
        const int g4 = (q << 7) + tid;                     // 0..511, contiguous per round
        const long long gi = gbase4 + g4;
        if (gi < lim4) {
            const int fr2 = g4 >> 2, e = g4 & 3;
            const float* rb = &ob[fr2 * OSTR + (e << 2)];
            out4[gi] = make_float4(rb[0], rb[1], rb[2], rb[3]);
        }
    }
}

extern "C" void kernel_launch(void* const* d_in, const int* in_sizes, int n_in,
                              void* d_out, int out_size, void* d_ws, size_t ws_size,
                              hipStream_t stream) {
    const float* x   = (const float*)d_in[0];
    float*      outp = (float*)d_out;
    int nframes = in_sizes[0] / NBINS;                 // 131072
    int nblocks = (nframes + FPB - 1) / FPB;           // 1024 = 4 blocks/CU, all resident
    plp_kernel<<<nblocks, FPB, 0, stream>>>(x, outp, nframes);
}